// Round 8
// baseline (240.444 us; speedup 1.0000x reference)
//
#include <hip/hip_runtime.h>
#include <math.h>

#define B_ 32
#define C_ 256
#define H_ 56
#define W_ 56
#define HW_ (H_*W_)        // 3136
#define Q_ (HW_/4)         // 784 float4 positions per (b,c) map
#define R_ 16
#define K_ 7

typedef float nat_f4 __attribute__((ext_vector_type(4)));

__device__ __forceinline__ float sigmoidf_(float v) { return 1.0f / (1.0f + __expf(-v)); }

__device__ __forceinline__ void nt_store4(float4 v, float4* p) {
    nat_f4 nv;
    nv.x = v.x; nv.y = v.y; nv.z = v.z; nv.w = v.w;
    __builtin_nontemporal_store(nv, (nat_f4*)p);
}

// ---------------------------------------------------------------------
// Block-parallel shared-MLP channel attention, recomputed per block.
// ---------------------------------------------------------------------
__device__ __forceinline__ void mlp_ca_block(int b,
        const float* __restrict__ avg, const float* __restrict__ mxv,
        const float* __restrict__ w1, const float* __restrict__ w2,
        float* sA, float* sM, float* hh, float* sca) {
    const int t = threadIdx.x;
    sA[t] = avg[b * C_ + t];
    sM[t] = mxv[b * C_ + t];
    __syncthreads();
    const int r = t >> 4, seg = t & 15;             // 16 threads per hidden unit
    float pa = 0.f, pm = 0.f;
    #pragma unroll
    for (int i = 0; i < 16; ++i) {
        const float wv = w1[r * C_ + seg * 16 + i];
        pa += wv * sA[seg * 16 + i];
        pm += wv * sM[seg * 16 + i];
    }
    #pragma unroll
    for (int off = 8; off >= 1; off >>= 1) {        // reduce across the 16-lane group
        pa += __shfl_xor(pa, off, 64);
        pm += __shfl_xor(pm, off, 64);
    }
    if (seg == 0) hh[r] = fmaxf(pa, 0.f) + fmaxf(pm, 0.f);
    __syncthreads();
    float acc = 0.f;
    #pragma unroll
    for (int rr = 0; rr < R_; ++rr) acc += w2[t * R_ + rr] * hh[rr];
    sca[t] = sigmoidf_(acc);
    __syncthreads();
}

// =====================================================================
// K1: per-(b,c) mean+max pooling. One wave per map, 4 maps per block.
// Plain stores; kernel boundary provides ordering/coherence.
// Grid: 2048 blocks x 256 threads.
// =====================================================================
__global__ void __launch_bounds__(256)
k_pool(const float* __restrict__ x, float* __restrict__ avg,
       float* __restrict__ mxv) {
    const int tid  = threadIdx.x;
    const int lane = tid & 63;
    const int wave = tid >> 6;
    const int map  = (blockIdx.x << 2) + wave;     // 0..8191

    const float4* xp = (const float4*)(x + (size_t)map * HW_);
    float s = 0.0f, m = -INFINITY;
    #pragma unroll
    for (int k = 0; k < 12; ++k) {                 // 12*64 = 768 of 784
        float4 v = xp[(k << 6) + lane];
        s += v.x + v.y + v.z + v.w;
        m = fmaxf(m, fmaxf(fmaxf(v.x, v.y), fmaxf(v.z, v.w)));
    }
    if (lane < 16) {                               // tail 768..783
        float4 v = xp[768 + lane];
        s += v.x + v.y + v.z + v.w;
        m = fmaxf(m, fmaxf(fmaxf(v.x, v.y), fmaxf(v.z, v.w)));
    }
    #pragma unroll
    for (int off = 32; off > 0; off >>= 1) {
        s += __shfl_xor(s, off, 64);
        m = fmaxf(m, __shfl_xor(m, off, 64));
    }
    if (lane == 0) {
        avg[map] = s * (1.0f / HW_);
        mxv[map] = m;
    }
}

// =====================================================================
// K2 (merged): MLP -> spatial-pool halo (recomputed per tile) -> 7x7
// conv + sigmoid -> residual finalize. Block = (b, 4-row tile).
// Grid: (14, 32) x 256 threads.
// =====================================================================
__global__ void __launch_bounds__(256)
k_sa_finalize(const float* __restrict__ x, const float* __restrict__ wsp,
              const float* __restrict__ avg, const float* __restrict__ mxv,
              const float* __restrict__ w1, const float* __restrict__ w2,
              float* __restrict__ out) {
    const int b    = blockIdx.y;
    const int r0   = blockIdx.x * 4;                // output rows r0..r0+3
    const int tid  = threadIdx.x;
    const int lane = tid & 63;
    const int w    = tid >> 6;                      // wave -> 64-channel slice

    __shared__ float  sA[C_], sM[C_], sca[C_], hh[R_];
    __shared__ float4 ps[4][140];                   // per-slice mean partials
    __shared__ float4 pm[4][140];                   // per-slice max partials
    __shared__ float  PH[2][10][62];                // padded {mean,max} planes
    __shared__ __align__(16) float ssa[224];        // sa for 4x56 positions
    __shared__ float  wc[2 * K_ * K_];

    if (tid < 2 * K_ * K_) wc[tid] = wsp[tid];
    mlp_ca_block(b, avg, mxv, w1, w2, sA, sM, hh, sca);  // ends in syncthreads

    // zero the 6 pad columns of each PH row: cols 0,1,2 and 59,60,61
    if (tid < 120) {
        const int plane = tid / 60, rem = tid % 60;
        const int hr = rem / 6, k = rem % 6;
        const int col = (k < 3) ? k : k + 56;       // 0,1,2,59,60,61  (FIXED)
        PH[plane][hr][col] = 0.f;
    }

    // ---- pooled halo: wave-slice accumulation, fully coalesced ----
    const float4* xb = (const float4*)(x + (size_t)b * C_ * HW_);
    const int qoff = (r0 - 3) * 14;                 // f4 offset of halo row 0
    #pragma unroll
    for (int chunk = 0; chunk < 3; ++chunk) {
        const int pf4 = chunk * 64 + lane;          // 0..139 halo f4 position
        if (pf4 < 140) {
            const int q = pf4 + qoff;               // f4 index within map
            float4 s = {0.f, 0.f, 0.f, 0.f};
            float4 m = {0.f, 0.f, 0.f, 0.f};        // OOB rows -> 0 (conv zero-pad)
            if (q >= 0 && q < Q_) {
                m.x = m.y = m.z = m.w = -INFINITY;
                #pragma unroll 8
                for (int i = 0; i < 64; ++i) {
                    const int c = (w << 6) + i;
                    const float a = sca[c];
                    float4 v = xb[(size_t)c * Q_ + q];
                    v.x *= a; v.y *= a; v.z *= a; v.w *= a;
                    s.x += v.x; s.y += v.y; s.z += v.z; s.w += v.w;
                    m.x = fmaxf(m.x, v.x); m.y = fmaxf(m.y, v.y);
                    m.z = fmaxf(m.z, v.z); m.w = fmaxf(m.w, v.w);
                }
            }
            ps[w][pf4] = s; pm[w][pf4] = m;
        }
    }
    __syncthreads();

    // ---- reduce 4 slices -> PH planes (mean, max) ----
    if (tid < 140) {
        float4 s = ps[0][tid], m = pm[0][tid];
        #pragma unroll
        for (int k = 1; k < 4; ++k) {
            float4 os = ps[k][tid], om = pm[k][tid];
            s.x += os.x; s.y += os.y; s.z += os.z; s.w += os.w;
            m.x = fmaxf(m.x, om.x); m.y = fmaxf(m.y, om.y);
            m.z = fmaxf(m.z, om.z); m.w = fmaxf(m.w, om.w);
        }
        const float inv = 1.0f / C_;
        const int hr = tid / 14, c4 = tid - hr * 14;
        float* pa = &PH[0][hr][3 + c4 * 4];
        float* pb = &PH[1][hr][3 + c4 * 4];
        pa[0] = s.x * inv; pa[1] = s.y * inv; pa[2] = s.z * inv; pa[3] = s.w * inv;
        pb[0] = m.x;       pb[1] = m.y;       pb[2] = m.z;       pb[3] = m.w;
    }
    __syncthreads();

    // ---- 7x7 conv + sigmoid over the 4x56 output positions ----
    if (tid < 224) {
        const int orow = tid / 56, ocol = tid - orow * 56;
        float acc = 0.0f;
        #pragma unroll
        for (int ky = 0; ky < K_; ++ky) {
            #pragma unroll
            for (int kx = 0; kx < K_; ++kx) {
                acc += wc[ky * K_ + kx]      * PH[0][orow + ky][ocol + kx]
                     + wc[49 + ky * K_ + kx] * PH[1][orow + ky][ocol + kx];
            }
        }
        ssa[tid] = sigmoidf_(acc);
    }
    __syncthreads();

    // ---- finalize: out = x*(1 + ca*sa), 8 channels in flight ----
    const int cg = tid >> 5;                        // 0..7
    const int ln = tid & 31;
    if (ln < 28) {
        float4* ob = (float4*)(out + (size_t)b * C_ * HW_);
        #pragma unroll
        for (int half = 0; half < 2; ++half) {
            const int pos = half * 28 + ln;         // 0..55 f4 within tile
            const float4 s4 = ((const float4*)ssa)[pos];
            const size_t base = (size_t)r0 * 14 + pos;
            #pragma unroll 4
            for (int g = 0; g < 32; ++g) {
                const int c = (g << 3) + cg;
                const float a = sca[c];
                const size_t o = (size_t)c * Q_ + base;
                float4 v = xb[o];
                float4 r;
                r.x = v.x * (1.0f + a * s4.x);
                r.y = v.y * (1.0f + a * s4.y);
                r.z = v.z * (1.0f + a * s4.z);
                r.w = v.w * (1.0f + a * s4.w);
                nt_store4(r, ob + o);
            }
        }
    }
}

extern "C" void kernel_launch(void* const* d_in, const int* in_sizes, int n_in,
                              void* d_out, int out_size, void* d_ws, size_t ws_size,
                              hipStream_t stream) {
    const float* x   = (const float*)d_in[0];
    const float* w1  = (const float*)d_in[1];
    const float* w2  = (const float*)d_in[2];
    const float* wsp = (const float*)d_in[3];
    float* out = (float*)d_out;

    // workspace layout (floats)
    float* ws  = (float*)d_ws;
    float* avg = ws;                                // B*C
    float* mx  = avg + B_ * C_;                     // B*C

    // K1: channel-wise pooling
    k_pool<<<(B_ * C_) / 4, 256, 0, stream>>>(x, avg, mx);

    // K2: MLP + spatial pool (halo recompute) + conv + finalize
    {
        dim3 g(H_ / 4, B_);
        k_sa_finalize<<<g, 256, 0, stream>>>(x, wsp, avg, mx, w1, w2, out);
    }
}

// Round 9
// 221.334 us; speedup vs baseline: 1.0863x; 1.0863x over previous
//
#include <hip/hip_runtime.h>
#include <math.h>

#define B_ 32
#define C_ 256
#define H_ 56
#define W_ 56
#define HW_ (H_*W_)        // 3136
#define Q_ (HW_/4)         // 784 float4 positions per (b,c) map
#define R_ 16
#define K_ 7

typedef float nat_f4 __attribute__((ext_vector_type(4)));

__device__ __forceinline__ float sigmoidf_(float v) { return 1.0f / (1.0f + __expf(-v)); }

__device__ __forceinline__ void nt_store4(float4 v, float4* p) {
    nat_f4 nv;
    nv.x = v.x; nv.y = v.y; nv.z = v.z; nv.w = v.w;
    __builtin_nontemporal_store(nv, (nat_f4*)p);
}

// ---------------------------------------------------------------------
// Block-parallel shared-MLP channel attention, recomputed per block.
// ---------------------------------------------------------------------
__device__ __forceinline__ void mlp_ca_block(int b,
        const float* __restrict__ avg, const float* __restrict__ mxv,
        const float* __restrict__ w1, const float* __restrict__ w2,
        float* sA, float* sM, float* hh, float* sca) {
    const int t = threadIdx.x;
    sA[t] = avg[b * C_ + t];
    sM[t] = mxv[b * C_ + t];
    __syncthreads();
    const int r = t >> 4, seg = t & 15;             // 16 threads per hidden unit
    float pa = 0.f, pm = 0.f;
    #pragma unroll
    for (int i = 0; i < 16; ++i) {
        const float wv = w1[r * C_ + seg * 16 + i];
        pa += wv * sA[seg * 16 + i];
        pm += wv * sM[seg * 16 + i];
    }
    #pragma unroll
    for (int off = 8; off >= 1; off >>= 1) {        // reduce across the 16-lane group
        pa += __shfl_xor(pa, off, 64);
        pm += __shfl_xor(pm, off, 64);
    }
    if (seg == 0) hh[r] = fmaxf(pa, 0.f) + fmaxf(pm, 0.f);
    __syncthreads();
    float acc = 0.f;
    #pragma unroll
    for (int rr = 0; rr < R_; ++rr) acc += w2[t * R_ + rr] * hh[rr];
    sca[t] = sigmoidf_(acc);
    __syncthreads();
}

// =====================================================================
// K1: per-(b,c) mean+max pooling. One wave per map, 4 maps per block.
// Grid: 2048 blocks x 256 threads.
// =====================================================================
__global__ void __launch_bounds__(256)
k_pool(const float* __restrict__ x, float* __restrict__ avg,
       float* __restrict__ mxv) {
    const int tid  = threadIdx.x;
    const int lane = tid & 63;
    const int wave = tid >> 6;
    const int map  = (blockIdx.x << 2) + wave;     // 0..8191

    const float4* xp = (const float4*)(x + (size_t)map * HW_);
    float s = 0.0f, m = -INFINITY;
    #pragma unroll
    for (int k = 0; k < 12; ++k) {                 // 12*64 = 768 of 784
        float4 v = xp[(k << 6) + lane];
        s += v.x + v.y + v.z + v.w;
        m = fmaxf(m, fmaxf(fmaxf(v.x, v.y), fmaxf(v.z, v.w)));
    }
    if (lane < 16) {                               // tail 768..783
        float4 v = xp[768 + lane];
        s += v.x + v.y + v.z + v.w;
        m = fmaxf(m, fmaxf(fmaxf(v.x, v.y), fmaxf(v.z, v.w)));
    }
    #pragma unroll
    for (int off = 32; off > 0; off >>= 1) {
        s += __shfl_xor(s, off, 64);
        m = fmaxf(m, __shfl_xor(m, off, 64));
    }
    if (lane == 0) {
        avg[map] = s * (1.0f / HW_);
        mxv[map] = m;
    }
}

// =====================================================================
// K2: spatial pooled = {mean_c, max_c} of x*ca, MLP fused per block.
// Reduction: in-wave shuffle across the wave's 4 channel groups, then
// one 4-way LDS fold. 2 block barriers (was 10).
// Grid: (49, 32) x 256 threads.
// =====================================================================
__global__ void __launch_bounds__(256)
k_spatial_pool(const float* __restrict__ x, const float* __restrict__ avg,
               const float* __restrict__ mxv, const float* __restrict__ w1,
               const float* __restrict__ w2, float* __restrict__ pooled) {
    const int b  = blockIdx.y;
    const int q0 = blockIdx.x * 16;
    const int t  = threadIdx.x;
    const int tq = t & 15;                          // q offset within block
    const int tc = t >> 4;                          // channel group 0..15
    const int w  = t >> 6;                          // wave 0..3
    const int q  = q0 + tq;

    __shared__ float sA[C_], sM[C_], sca[C_], hh[R_];
    mlp_ca_block(b, avg, mxv, w1, w2, sA, sM, hh, sca);  // ends in syncthreads

    const float4* xp = (const float4*)(x + (size_t)b * C_ * HW_);

    float4 s = {0.f, 0.f, 0.f, 0.f};
    float4 m = {-INFINITY, -INFINITY, -INFINITY, -INFINITY};
    #pragma unroll 4
    for (int i = 0; i < 16; ++i) {
        const int c = tc * 16 + i;
        const float a = sca[c];
        float4 v = xp[(size_t)c * Q_ + q];
        v.x *= a; v.y *= a; v.z *= a; v.w *= a;
        s.x += v.x; s.y += v.y; s.z += v.z; s.w += v.w;
        m.x = fmaxf(m.x, v.x); m.y = fmaxf(m.y, v.y);
        m.z = fmaxf(m.z, v.z); m.w = fmaxf(m.w, v.w);
    }

    // in-wave reduce across the wave's 4 channel groups (lanes differ in
    // bits 4,5 of lane index; same tq every 16 lanes)
    #pragma unroll
    for (int off = 16; off <= 32; off <<= 1) {
        s.x += __shfl_xor(s.x, off, 64);
        s.y += __shfl_xor(s.y, off, 64);
        s.z += __shfl_xor(s.z, off, 64);
        s.w += __shfl_xor(s.w, off, 64);
        m.x = fmaxf(m.x, __shfl_xor(m.x, off, 64));
        m.y = fmaxf(m.y, __shfl_xor(m.y, off, 64));
        m.z = fmaxf(m.z, __shfl_xor(m.z, off, 64));
        m.w = fmaxf(m.w, __shfl_xor(m.w, off, 64));
    }

    __shared__ float4 ws_[4][16];
    __shared__ float4 wm_[4][16];
    if ((t & 63) < 16) { ws_[w][tq] = s; wm_[w][tq] = m; }
    __syncthreads();

    if (t < 16) {                                   // final 4-way fold, wave 0
        float4 fs = ws_[0][t], fm = wm_[0][t];
        #pragma unroll
        for (int k = 1; k < 4; ++k) {
            float4 os = ws_[k][t], om = wm_[k][t];
            fs.x += os.x; fs.y += os.y; fs.z += os.z; fs.w += os.w;
            fm.x = fmaxf(fm.x, om.x); fm.y = fmaxf(fm.y, om.y);
            fm.z = fmaxf(fm.z, om.z); fm.w = fmaxf(fm.w, om.w);
        }
        const float inv = 1.0f / C_;
        float4 sm4 = {fs.x * inv, fs.y * inv, fs.z * inv, fs.w * inv};
        ((float4*)(pooled + (size_t)b * 2 * HW_))[q0 + t]       = sm4;
        ((float4*)(pooled + (size_t)b * 2 * HW_ + HW_))[q0 + t] = fm;
    }
}

// =====================================================================
// K3: 7x7 conv + sigmoid -> sa (in LDS) fused with residual finalize,
// MLP fused per block. Block = (b, 2-row tile). Grid: (28, 32) x 256.
// =====================================================================
__global__ void __launch_bounds__(256)
k_conv_finalize(const float* __restrict__ x, const float* __restrict__ pooled,
                const float* __restrict__ wsp, const float* __restrict__ avg,
                const float* __restrict__ mxv, const float* __restrict__ w1,
                const float* __restrict__ w2, float* __restrict__ out) {
    const int b   = blockIdx.y;
    const int r0  = blockIdx.x * 2;                 // output rows r0, r0+1
    const int tid = threadIdx.x;

    __shared__ float PH[2][8][62];                  // [plane][halo row][padded col]
    __shared__ __align__(16) float ssa[112];        // sa for the 112 tile positions
    __shared__ float sA[C_], sM[C_], sca[C_], hh[R_];
    __shared__ float wc[2 * K_ * K_];

    if (tid < 2 * K_ * K_) wc[tid] = wsp[tid];
    mlp_ca_block(b, avg, mxv, w1, w2, sA, sM, hh, sca);

    // halo load: 2 planes x 8 rows x 62 cols = 992 entries, zero-padded OOB
    for (int idx = tid; idx < 992; idx += 256) {
        const int plane = idx / 496;
        const int rem   = idx - plane * 496;
        const int lr    = rem / 62;
        const int cpad  = rem - lr * 62;
        const int row   = r0 - 3 + lr;
        const int col   = cpad - 3;
        float v = 0.0f;
        if (row >= 0 && row < H_ && col >= 0 && col < W_)
            v = pooled[((size_t)b * 2 + plane) * HW_ + row * W_ + col];
        PH[plane][lr][cpad] = v;
    }
    __syncthreads();

    // conv 7x7 over the 112 tile positions (zero-padded => no branches)
    if (tid < 112) {
        const int prow = tid / 56;
        const int pcol = tid - prow * 56;
        float acc = 0.0f;
        #pragma unroll
        for (int ky = 0; ky < K_; ++ky) {
            #pragma unroll
            for (int kx = 0; kx < K_; ++kx) {
                acc += wc[ky * K_ + kx]      * PH[0][prow + ky][pcol + kx]
                     + wc[49 + ky * K_ + kx] * PH[1][prow + ky][pcol + kx];
            }
        }
        ssa[tid] = sigmoidf_(acc);
    }
    __syncthreads();

    // finalize: 8 channels in flight, 28 float4 lanes each (112 floats/ch)
    const int cg   = tid >> 5;                      // 0..7
    const int lane = tid & 31;
    if (lane < 28) {
        const float4* xb = (const float4*)(x + (size_t)b * C_ * HW_);
        float4* ob = (float4*)(out + (size_t)b * C_ * HW_);
        const int base = r0 * 14;                   // float4 offset of row r0
        const float4 s4 = ((const float4*)ssa)[lane];
        #pragma unroll 4
        for (int g = 0; g < 32; ++g) {
            const int c = (g << 3) + cg;
            const float a = sca[c];
            const size_t o = (size_t)c * Q_ + base + lane;
            float4 v = xb[o];
            float4 r;
            r.x = v.x * (1.0f + a * s4.x);
            r.y = v.y * (1.0f + a * s4.y);
            r.z = v.z * (1.0f + a * s4.z);
            r.w = v.w * (1.0f + a * s4.w);
            nt_store4(r, ob + o);
        }
    }
}

extern "C" void kernel_launch(void* const* d_in, const int* in_sizes, int n_in,
                              void* d_out, int out_size, void* d_ws, size_t ws_size,
                              hipStream_t stream) {
    const float* x   = (const float*)d_in[0];
    const float* w1  = (const float*)d_in[1];
    const float* w2  = (const float*)d_in[2];
    const float* wsp = (const float*)d_in[3];
    float* out = (float*)d_out;

    // workspace layout (floats)
    float* ws     = (float*)d_ws;
    float* avg    = ws;                             // B*C
    float* mx     = avg + B_ * C_;                  // B*C
    float* pooled = mx + B_ * C_;                   // B*2*HW

    // K1: channel-wise pooling
    k_pool<<<(B_ * C_) / 4, 256, 0, stream>>>(x, avg, mx);

    // K2: spatial pooling of x*ca (MLP fused per block)
    {
        dim3 g(Q_ / 16, B_);
        k_spatial_pool<<<g, 256, 0, stream>>>(x, avg, mx, w1, w2, pooled);
    }

    // K3: 7x7 conv + sigmoid + residual finalize (MLP fused per block)
    {
        dim3 g(H_ / 2, B_);
        k_conv_finalize<<<g, 256, 0, stream>>>(x, pooled, wsp, avg, mx, w1, w2, out);
    }
}